// Round 4
// baseline (304.476 us; speedup 1.0000x reference)
//
#include <hip/hip_runtime.h>
#include <math.h>

#define WAVE_LDS_FENCE() asm volatile("s_waitcnt lgkmcnt(0)" ::: "memory")

constexpr int Nn = 16384;
constexpr int WAVES = 4;   // waves per block
constexpr int PTS = 8;     // points per wave (2 groups of 4)

// ---- DPP helpers (pure VALU cross-lane) ----
template <int CTRL>
__device__ __forceinline__ float dpp_f(float x) {
    return __int_as_float(
        __builtin_amdgcn_update_dpp(0, __float_as_int(x), CTRL, 0xF, 0xF, false));
}
__device__ __forceinline__ float rsum16(float v) {   // row-of-16 sum, in all 16 lanes
    v += dpp_f<0x128>(v); v += dpp_f<0x124>(v);
    v += dpp_f<0x122>(v); v += dpp_f<0x121>(v);
    return v;
}
__device__ __forceinline__ float rmax16(float v) {
    v = fmaxf(v, dpp_f<0x128>(v)); v = fmaxf(v, dpp_f<0x124>(v));
    v = fmaxf(v, dpp_f<0x122>(v)); v = fmaxf(v, dpp_f<0x121>(v));
    return v;
}
__device__ __forceinline__ float lanebc(float v, int l) {   // wave-uniform lane read
    return __int_as_float(__builtin_amdgcn_readlane(__float_as_int(v), l));
}
__device__ __forceinline__ float sum64(float v) {   // full-wave sum, 0 DS ops
    v = rsum16(v);
    v += dpp_f<0x142>(v);   // row_bcast15
    v += dpp_f<0x143>(v);   // row_bcast31
    return lanebc(v, 63);
}

__global__ __launch_bounds__(256, 4) void pt_attn_kernel(
    const float* __restrict__ xyz,      // [B,3,N]
    const float* __restrict__ nxyz,     // [B,3,N,S]
    const float* __restrict__ points,   // [B,C,N]
    const float* __restrict__ npts,     // [B,C,N,S]
    const float* __restrict__ Wk,       // [C,C]
    const float* __restrict__ Wv,      // [64,C+3]
    const float* __restrict__ Wp,       // [C,4]
    float* __restrict__ out)            // [B,64,N]
{
    __shared__ float wk_lds[64 * 64];                 // [o][c] row-major (reads 2-way free)
    __shared__ float wvT_lds[67 * 65];                // [c][o], pad-65 rows (2-way free)
    __shared__ float wp_lds[64 * 5];                  // [c][j], pad-5 rows
    __shared__ __align__(16) float qk_lds[WAVES][4 * 68];   // per-wave [nn][c], pad-68

    const int tid = threadIdx.x;
    const int w = tid >> 6;
    const int lane = tid & 63;
    const int s = lane & 15;        // neighbor index role
    const int nn = lane >> 4;       // point-within-group role

    // ---- cooperative one-time weight staging (coalesced global reads) ----
    for (int idx = tid; idx < 64 * 64; idx += 256) wk_lds[idx] = Wk[idx];
    for (int idx = tid; idx < 64 * 67; idx += 256) {
        const int o = idx / 67, c = idx - o * 67;
        wvT_lds[c * 65 + o] = Wv[idx];
    }
    {
        const int c = tid >> 2, j = tid & 3;   // 256 threads cover 64*4 exactly
        wp_lds[c * 5 + j] = Wp[tid];
    }
    __syncthreads();

    const int pt0 = blockIdx.x * (WAVES * PTS) + w * PTS;
    const int b = pt0 >> 14;
    const int n0 = pt0 & (Nn - 1);

    // per-lane Wp row (lane = c role); bp dropped (constant-in-s, cancels in softmax)
    const float wpj0 = wp_lds[lane * 5 + 0];
    const float wpj1 = wp_lds[lane * 5 + 1];
    const float wpj2 = wp_lds[lane * 5 + 2];
    const float wpj3 = wp_lds[lane * 5 + 3];

#pragma unroll 1
    for (int g = 0; g < 2; ++g) {
        const int ng = n0 + 4 * g;

        // ---- q for the 4 points (lane = c role), scale folded in ----
        const float4 qg = *(const float4*)(points + (size_t)(b * 64 + lane) * Nn + ng);
        const float q0 = qg.x * 0.125f, q1 = qg.y * 0.125f;
        const float q2 = qg.z * 0.125f, q3 = qg.w * 0.125f;

        // ---- np stream: 64 fully-coalesced dwords into registers ----
        float npv[64];
#pragma unroll
        for (int i = 0; i < 64; ++i)
            npv[i] = npts[((size_t)(b * 64 + i) * Nn + ng + nn) * 16 + s];

        // ---- relative position for this lane's (nn, s) ----
        const float nx0 = nxyz[((size_t)(b * 3 + 0) * Nn + ng + nn) * 16 + s];
        const float nx1 = nxyz[((size_t)(b * 3 + 1) * Nn + ng + nn) * 16 + s];
        const float nx2 = nxyz[((size_t)(b * 3 + 2) * Nn + ng + nn) * 16 + s];
        const float x0 = xyz[(size_t)(b * 3 + 0) * Nn + ng + nn];
        const float x1 = xyz[(size_t)(b * 3 + 1) * Nn + ng + nn];
        const float x2 = xyz[(size_t)(b * 3 + 2) * Nn + ng + nn];
        const float d0 = x0 - nx0, d1 = x1 - nx1, d2 = x2 - nx2;
        const float dn = sqrtf(d0 * d0 + d1 * d1 + d2 * d2);

        // ---- phase 0 (lane = c): qk[c,nn] = sum_o q[o,nn] * Wk[o][c] ----
        float qk0 = 0.f, qk1 = 0.f, qk2 = 0.f, qk3 = 0.f;
#pragma unroll
        for (int o = 0; o < 64; ++o) {
            const float wkv = wk_lds[o * 64 + lane];   // 2-way (free) LDS read
            qk0 = fmaf(lanebc(q0, o), wkv, qk0);
            qk1 = fmaf(lanebc(q1, o), wkv, qk1);
            qk2 = fmaf(lanebc(q2, o), wkv, qk2);
            qk3 = fmaf(lanebc(q3, o), wkv, qk3);
        }

        // WAR fence (qk_lds reused across g), then publish qk
        WAVE_LDS_FENCE();
        {
            float* qkrow = &qk_lds[w][0];
            qkrow[0 * 68 + lane] = qk0;
            qkrow[1 * 68 + lane] = qk1;
            qkrow[2 * 68 + lane] = qk2;
            qkrow[3 * 68 + lane] = qk3;
        }

        // ---- pp[j,nn] = sum_c qk[c,nn]*Wp[c][j] (pure DPP), select own nn ----
        float p[4];
#pragma unroll
        for (int j = 0; j < 4; ++j) {
            const float wpv = (j == 0) ? wpj0 : (j == 1) ? wpj1 : (j == 2) ? wpj2 : wpj3;
            const float s0 = sum64(qk0 * wpv);
            const float s1 = sum64(qk1 * wpv);
            const float s2 = sum64(qk2 * wpv);
            const float s3 = sum64(qk3 * wpv);
            const float aa = (nn & 1) ? s1 : s0;
            const float bb = (nn & 1) ? s3 : s2;
            p[j] = (nn & 2) ? bb : aa;
        }

        WAVE_LDS_FENCE();   // qk_lds writes visible to own wave

        // ---- phase 1 (lane = (nn,s)): logit = sum_c qk[c,nn]*np[c] + pp·pos ----
        const float4* qkp = (const float4*)&qk_lds[w][nn * 68];
        float l0 = 0.f, l1 = 0.f, l2 = 0.f, l3 = 0.f;
#pragma unroll
        for (int cq = 0; cq < 16; ++cq) {
            const float4 qq = qkp[cq];     // bank-disjoint b128 broadcast
            l0 = fmaf(qq.x, npv[4 * cq + 0], l0);
            l1 = fmaf(qq.y, npv[4 * cq + 1], l1);
            l2 = fmaf(qq.z, npv[4 * cq + 2], l2);
            l3 = fmaf(qq.w, npv[4 * cq + 3], l3);
        }
        float logit = (l0 + l1) + (l2 + l3);
        logit += p[0] * d0 + p[1] * d1 + p[2] * d2 + p[3] * dn;

        // ---- softmax over s (pure DPP within 16-lane groups) ----
        const float mx = rmax16(logit);
        const float e = __expf(logit - mx);
        const float se = rsum16(e);
        const float attn = e / se;

        // ---- phase 2: vbar[c,nn] = sum_s attn*np[c]; keep in 5 named regs ----
        float vb0 = 0.f, vb1 = 0.f, vb2 = 0.f, vb3 = 0.f, vb4 = 0.f;
#pragma unroll
        for (int i = 0; i < 64; ++i) {
            const float r = rsum16(attn * npv[i]);
            const bool sel = (s == (i & 15));
            if ((i >> 4) == 0) vb0 = sel ? r : vb0;
            if ((i >> 4) == 1) vb1 = sel ? r : vb1;
            if ((i >> 4) == 2) vb2 = sel ? r : vb2;
            if ((i >> 4) == 3) vb3 = sel ? r : vb3;
        }
        {   // tail channels 64..66 (= tmp d0,d1,d2)
            const float t0 = rsum16(attn * d0);
            const float t1 = rsum16(attn * d1);
            const float t2 = rsum16(attn * d2);
            vb4 = (s == 0) ? t0 : (s == 1) ? t1 : (s == 2) ? t2 : 0.0f;
        }

        // ---- phase 3 (lane = o): out[o,nn] = sum_c Wv[o][c]*vbar[c,nn] ----
        float a0 = 0.f, a1 = 0.f, a2 = 0.f, a3 = 0.f;
#pragma unroll
        for (int c = 0; c < 67; ++c) {
            const float wvv = wvT_lds[c * 65 + lane];   // 2-way (free) LDS read
            const float vbsrc = (c < 16) ? vb0 : (c < 32) ? vb1
                              : (c < 48) ? vb2 : (c < 64) ? vb3 : vb4;
            a0 = fmaf(lanebc(vbsrc, 0 * 16 + (c & 15)), wvv, a0);
            a1 = fmaf(lanebc(vbsrc, 1 * 16 + (c & 15)), wvv, a1);
            a2 = fmaf(lanebc(vbsrc, 2 * 16 + (c & 15)), wvv, a2);
            a3 = fmaf(lanebc(vbsrc, 3 * 16 + (c & 15)), wvv, a3);
        }

        *(float4*)(out + (size_t)(b * 64 + lane) * Nn + ng) = make_float4(a0, a1, a2, a3);
    }
}

extern "C" void kernel_launch(void* const* d_in, const int* in_sizes, int n_in,
                              void* d_out, int out_size, void* d_ws, size_t ws_size,
                              hipStream_t stream) {
    const float* xyz    = (const float*)d_in[0];
    const float* nxyz   = (const float*)d_in[1];
    const float* points = (const float*)d_in[2];
    const float* npts   = (const float*)d_in[3];
    const float* Wk     = (const float*)d_in[4];
    const float* Wv     = (const float*)d_in[5];
    const float* Wp     = (const float*)d_in[6];
    // d_in[7] = bp — unused: constant-in-s logit shift cancels in softmax
    float* out = (float*)d_out;

    const int total_pts = 4 * Nn;                    // B*N = 65536
    const int blocks = total_pts / (WAVES * PTS);    // 2048

    hipLaunchKernelGGL(pt_attn_kernel, dim3(blocks), dim3(256), 0, stream,
                       xyz, nxyz, points, npts, Wk, Wv, Wp, out);
}

// Round 5
// 188.596 us; speedup vs baseline: 1.6144x; 1.6144x over previous
//
#include <hip/hip_runtime.h>
#include <math.h>

constexpr int Nn = 16384;
constexpr int ST = 68;                      // ws row stride (dwords): 64 qk + 4 pp (reused as 64 vbar + 3 tail + 0)
constexpr size_t NS = (size_t)Nn * 16;      // dwords per channel plane of npts

// ---- DPP helpers (pure VALU cross-lane, rows of 16) ----
template <int CTRL>
__device__ __forceinline__ float dpp_f(float x) {
    return __int_as_float(
        __builtin_amdgcn_update_dpp(0, __float_as_int(x), CTRL, 0xF, 0xF, false));
}
__device__ __forceinline__ float rsum16(float v) {
    v += dpp_f<0x128>(v); v += dpp_f<0x124>(v);
    v += dpp_f<0x122>(v); v += dpp_f<0x121>(v);
    return v;
}
__device__ __forceinline__ float rmax16(float v) {
    v = fmaxf(v, dpp_f<0x128>(v)); v = fmaxf(v, dpp_f<0x124>(v));
    v = fmaxf(v, dpp_f<0x122>(v)); v = fmaxf(v, dpp_f<0x121>(v));
    return v;
}

// ================= Kernel A: qk = Wk^T (q*scale), pp = Wp^T qk =================
// thread = (point, 16-channel quarter); no LDS.
__global__ __launch_bounds__(256, 4) void qkpp_kernel(
    const float* __restrict__ points, const float* __restrict__ Wk,
    const float* __restrict__ Wp, float* __restrict__ ws)
{
    const int tid = threadIdx.x;
    const int lane = tid & 63;
    const int q = lane >> 4;                            // quarter 0..3
    const int pt = blockIdx.x * 64 + (tid >> 6) * 16 + (lane & 15);
    const int b = pt >> 14;
    const int n = pt & (Nn - 1);

    float qk[16];
#pragma unroll
    for (int k = 0; k < 16; ++k) qk[k] = 0.f;

    const float* prow = points + (size_t)b * 64 * Nn + n;
    const float* wkq = Wk + 16 * q;
#pragma unroll 4
    for (int c = 0; c < 64; ++c) {
        const float qv = prow[(size_t)c * Nn];          // coalesced (16n x4 dup -> 64B)
        const float4 w0 = *(const float4*)(wkq + c * 64 + 0);   // wave-broadcast (4 distinct)
        const float4 w1 = *(const float4*)(wkq + c * 64 + 4);
        const float4 w2 = *(const float4*)(wkq + c * 64 + 8);
        const float4 w3 = *(const float4*)(wkq + c * 64 + 12);
        qk[0]  = fmaf(qv, w0.x, qk[0]);  qk[1]  = fmaf(qv, w0.y, qk[1]);
        qk[2]  = fmaf(qv, w0.z, qk[2]);  qk[3]  = fmaf(qv, w0.w, qk[3]);
        qk[4]  = fmaf(qv, w1.x, qk[4]);  qk[5]  = fmaf(qv, w1.y, qk[5]);
        qk[6]  = fmaf(qv, w1.z, qk[6]);  qk[7]  = fmaf(qv, w1.w, qk[7]);
        qk[8]  = fmaf(qv, w2.x, qk[8]);  qk[9]  = fmaf(qv, w2.y, qk[9]);
        qk[10] = fmaf(qv, w2.z, qk[10]); qk[11] = fmaf(qv, w2.w, qk[11]);
        qk[12] = fmaf(qv, w3.x, qk[12]); qk[13] = fmaf(qv, w3.y, qk[13]);
        qk[14] = fmaf(qv, w3.z, qk[14]); qk[15] = fmaf(qv, w3.w, qk[15]);
    }
#pragma unroll
    for (int k = 0; k < 16; ++k) qk[k] *= 0.125f;       // fold SCALE

    // pp[j] = sum_c qk[c] * Wp[c][j]  (partial over own quarter, combine via shfl)
    float p0 = 0.f, p1 = 0.f, p2 = 0.f, p3 = 0.f;
#pragma unroll
    for (int k = 0; k < 16; ++k) {
        const float4 wp4 = *(const float4*)(Wp + (16 * q + k) * 4);
        p0 = fmaf(qk[k], wp4.x, p0);
        p1 = fmaf(qk[k], wp4.y, p1);
        p2 = fmaf(qk[k], wp4.z, p2);
        p3 = fmaf(qk[k], wp4.w, p3);
    }
    p0 += __shfl_xor(p0, 16); p0 += __shfl_xor(p0, 32);
    p1 += __shfl_xor(p1, 16); p1 += __shfl_xor(p1, 32);
    p2 += __shfl_xor(p2, 16); p2 += __shfl_xor(p2, 32);
    p3 += __shfl_xor(p3, 16); p3 += __shfl_xor(p3, 32);

    float* orow = ws + (size_t)pt * ST + 16 * q;
    ((float4*)orow)[0] = make_float4(qk[0],  qk[1],  qk[2],  qk[3]);
    ((float4*)orow)[1] = make_float4(qk[4],  qk[5],  qk[6],  qk[7]);
    ((float4*)orow)[2] = make_float4(qk[8],  qk[9],  qk[10], qk[11]);
    ((float4*)orow)[3] = make_float4(qk[12], qk[13], qk[14], qk[15]);
    if (q == 0)
        *(float4*)(ws + (size_t)pt * ST + 64) = make_float4(p0, p1, p2, p3);
}

// ============ Kernel B: logits + softmax + vbar (the 256MB streamer) ============
// wave = 4 points, lane = (nn, s); zero LDS, zero barriers; in-place ws row reuse.
__global__ __launch_bounds__(256, 6) void attn_vbar_kernel(
    const float* __restrict__ xyz, const float* __restrict__ nxyz,
    const float* __restrict__ npts, float* __restrict__ ws)
{
    const int tid = threadIdx.x;
    const int lane = tid & 63;
    const int s = lane & 15;
    const int nn = lane >> 4;
    const int gpt = blockIdx.x * 16 + (tid >> 6) * 4;   // 4-point group base
    const int b = gpt >> 14;
    const int ng = gpt & (Nn - 1);
    const int pt = gpt + nn;                            // this lane's point

    const float* npb = npts + (size_t)(b * 64) * NS + (size_t)ng * 16 + lane;  // +c*NS
    const float* qrow = ws + (size_t)pt * ST;

    // relative position (lane's (nn,s)); all loads fully coalesced (lane-linear)
    const float nx0 = nxyz[((size_t)(b * 3 + 0) * Nn + ng) * 16 + lane];
    const float nx1 = nxyz[((size_t)(b * 3 + 1) * Nn + ng) * 16 + lane];
    const float nx2 = nxyz[((size_t)(b * 3 + 2) * Nn + ng) * 16 + lane];
    const float x0 = xyz[(size_t)(b * 3 + 0) * Nn + ng + nn];
    const float x1 = xyz[(size_t)(b * 3 + 1) * Nn + ng + nn];
    const float x2 = xyz[(size_t)(b * 3 + 2) * Nn + ng + nn];
    const float d0 = x0 - nx0, d1 = x1 - nx1, d2 = x2 - nx2;
    const float dn = sqrtf(d0 * d0 + d1 * d1 + d2 * d2);

    // ---- logit = qk . np  (np: 256B/instr coalesced; qk: 16B broadcast) ----
    float l0 = 0.f, l1 = 0.f, l2 = 0.f, l3 = 0.f;
#pragma unroll 4
    for (int jc = 0; jc < 16; ++jc) {
        const float4 qq = *(const float4*)(qrow + 4 * jc);
        l0 = fmaf(qq.x, npb[(size_t)(4 * jc + 0) * NS], l0);
        l1 = fmaf(qq.y, npb[(size_t)(4 * jc + 1) * NS], l1);
        l2 = fmaf(qq.z, npb[(size_t)(4 * jc + 2) * NS], l2);
        l3 = fmaf(qq.w, npb[(size_t)(4 * jc + 3) * NS], l3);
    }
    const float4 ppv = *(const float4*)(qrow + 64);
    float logit = (l0 + l1) + (l2 + l3);
    logit += ppv.x * d0 + ppv.y * d1 + ppv.z * d2 + ppv.w * dn;
    // (bp term constant in s -> cancels in softmax)

    // ---- softmax over s (pure DPP in rows of 16) ----
    const float mx = rmax16(logit);
    const float e = __expf(logit - mx);
    const float se = rsum16(e);
    const float attn = e / se;

    // ---- vbar[c] = sum_s attn*np[c][s]; np re-read (L2-hot, 16KB/wave set) ----
    // all qrow reads above complete before these in-place writes (program order,
    // row is wave-private) -> safe buffer reuse.
    float* vrow = ws + (size_t)pt * ST;
#pragma unroll
    for (int k = 0; k < 4; ++k) {               // k compile-time -> static everywhere
        float sel = 0.f;
#pragma unroll 8
        for (int c2 = 0; c2 < 16; ++c2) {
            const float r = rsum16(attn * npb[(size_t)(16 * k + c2) * NS]);
            sel = (s == c2) ? r : sel;          // lane keeps c = 16k + s
        }
        vrow[16 * k + s] = sel;                 // 16 consec dwords x4 pts / instr
    }
    const float t0 = rsum16(attn * d0);
    const float t1 = rsum16(attn * d1);
    const float t2 = rsum16(attn * d2);
    if (s < 4) {
        const float tv = (s == 0) ? t0 : (s == 1) ? t1 : (s == 2) ? t2 : 0.f;
        vrow[64 + s] = tv;                      // tail channels 64..66, slot 67 = 0
    }
}

// ================= Kernel C: out[o] = Wv[o,:] . vbar =================
// lane = o, Wv row in regs; vbar via full-wave 16B broadcast loads; no LDS.
__global__ __launch_bounds__(256, 4) void out_kernel(
    const float* __restrict__ Wv, const float* __restrict__ ws,
    float* __restrict__ out)
{
    const int tid = threadIdx.x;
    const int lane = tid & 63;                  // output channel o
    const int cpt = blockIdx.x * 64 + (tid >> 6) * 16;   // 16 consecutive points
    const int b = cpt >> 14;
    const int n0 = cpt & (Nn - 1);

    float wv[68];
#pragma unroll
    for (int c = 0; c < 67; ++c) wv[c] = Wv[lane * 67 + c];
    wv[67] = 0.f;                               // pairs with the zeroed ws slot 67

    float acc[16];
    const float* vbase = ws + (size_t)cpt * ST;
#pragma unroll
    for (int i = 0; i < 16; ++i) {
        float a0 = 0.f, a1 = 0.f, a2 = 0.f, a3 = 0.f;
#pragma unroll
        for (int j = 0; j < 17; ++j) {
            const float4 vv = *(const float4*)(vbase + i * ST + 4 * j);  // 1-addr broadcast
            a0 = fmaf(vv.x, wv[4 * j + 0], a0);
            a1 = fmaf(vv.y, wv[4 * j + 1], a1);
            a2 = fmaf(vv.z, wv[4 * j + 2], a2);
            a3 = fmaf(vv.w, wv[4 * j + 3], a3);
        }
        acc[i] = (a0 + a1) + (a2 + a3);
    }
    // 64B contiguous per lane; 4-wave block covers 256B runs per (b,o) row
    float* orow = out + (size_t)(b * 64 + lane) * Nn + n0;
    ((float4*)orow)[0] = make_float4(acc[0],  acc[1],  acc[2],  acc[3]);
    ((float4*)orow)[1] = make_float4(acc[4],  acc[5],  acc[6],  acc[7]);
    ((float4*)orow)[2] = make_float4(acc[8],  acc[9],  acc[10], acc[11]);
    ((float4*)orow)[3] = make_float4(acc[12], acc[13], acc[14], acc[15]);
}

extern "C" void kernel_launch(void* const* d_in, const int* in_sizes, int n_in,
                              void* d_out, int out_size, void* d_ws, size_t ws_size,
                              hipStream_t stream) {
    const float* xyz    = (const float*)d_in[0];
    const float* nxyz   = (const float*)d_in[1];
    const float* points = (const float*)d_in[2];
    const float* npts   = (const float*)d_in[3];
    const float* Wk     = (const float*)d_in[4];
    const float* Wv     = (const float*)d_in[5];
    const float* Wp     = (const float*)d_in[6];
    // d_in[7] = bp — unused: constant-in-s logit shift cancels in softmax
    float* out = (float*)d_out;
    float* ws = (float*)d_ws;   // [65536][68] fp32 = 17.8 MB, fully rewritten each call

    hipLaunchKernelGGL(qkpp_kernel,      dim3(1024), dim3(256), 0, stream,
                       points, Wk, Wp, ws);
    hipLaunchKernelGGL(attn_vbar_kernel, dim3(4096), dim3(256), 0, stream,
                       xyz, nxyz, npts, ws);
    hipLaunchKernelGGL(out_kernel,       dim3(1024), dim3(256), 0, stream,
                       Wv, ws, out);
}

// Round 6
// 158.029 us; speedup vs baseline: 1.9267x; 1.1934x over previous
//
#include <hip/hip_runtime.h>
#include <math.h>

constexpr int Nn = 16384;
constexpr int ST = 68;                      // ws row stride (dwords): 64 qk + 4 pp (reused as 64 vbar + 3 tail + 0)
constexpr size_t NS = (size_t)Nn * 16;      // dwords per channel plane of npts

// ---- DPP helpers (pure VALU cross-lane, rows of 16) ----
template <int CTRL>
__device__ __forceinline__ float dpp_f(float x) {
    return __int_as_float(
        __builtin_amdgcn_update_dpp(0, __float_as_int(x), CTRL, 0xF, 0xF, false));
}
__device__ __forceinline__ float rsum16(float v) {
    v += dpp_f<0x128>(v); v += dpp_f<0x124>(v);
    v += dpp_f<0x122>(v); v += dpp_f<0x121>(v);
    return v;
}
__device__ __forceinline__ float rmax16(float v) {
    v = fmaxf(v, dpp_f<0x128>(v)); v = fmaxf(v, dpp_f<0x124>(v));
    v = fmaxf(v, dpp_f<0x122>(v)); v = fmaxf(v, dpp_f<0x121>(v));
    return v;
}

// ================= Kernel A: qk = Wk^T (q*scale), pp = Wp^T qk =================
// thread = (point, 16-channel quarter); no LDS.
__global__ __launch_bounds__(256, 4) void qkpp_kernel(
    const float* __restrict__ points, const float* __restrict__ Wk,
    const float* __restrict__ Wp, float* __restrict__ ws)
{
    const int tid = threadIdx.x;
    const int lane = tid & 63;
    const int q = lane >> 4;                            // quarter 0..3
    const int pt = blockIdx.x * 64 + (tid >> 6) * 16 + (lane & 15);
    const int b = pt >> 14;
    const int n = pt & (Nn - 1);

    float qk[16];
#pragma unroll
    for (int k = 0; k < 16; ++k) qk[k] = 0.f;

    const float* prow = points + (size_t)b * 64 * Nn + n;
    const float* wkq = Wk + 16 * q;
#pragma unroll 4
    for (int c = 0; c < 64; ++c) {
        const float qv = prow[(size_t)c * Nn];          // coalesced (16n x4 dup -> 64B)
        const float4 w0 = *(const float4*)(wkq + c * 64 + 0);   // wave-broadcast (4 distinct)
        const float4 w1 = *(const float4*)(wkq + c * 64 + 4);
        const float4 w2 = *(const float4*)(wkq + c * 64 + 8);
        const float4 w3 = *(const float4*)(wkq + c * 64 + 12);
        qk[0]  = fmaf(qv, w0.x, qk[0]);  qk[1]  = fmaf(qv, w0.y, qk[1]);
        qk[2]  = fmaf(qv, w0.z, qk[2]);  qk[3]  = fmaf(qv, w0.w, qk[3]);
        qk[4]  = fmaf(qv, w1.x, qk[4]);  qk[5]  = fmaf(qv, w1.y, qk[5]);
        qk[6]  = fmaf(qv, w1.z, qk[6]);  qk[7]  = fmaf(qv, w1.w, qk[7]);
        qk[8]  = fmaf(qv, w2.x, qk[8]);  qk[9]  = fmaf(qv, w2.y, qk[9]);
        qk[10] = fmaf(qv, w2.z, qk[10]); qk[11] = fmaf(qv, w2.w, qk[11]);
        qk[12] = fmaf(qv, w3.x, qk[12]); qk[13] = fmaf(qv, w3.y, qk[13]);
        qk[14] = fmaf(qv, w3.z, qk[14]); qk[15] = fmaf(qv, w3.w, qk[15]);
    }
#pragma unroll
    for (int k = 0; k < 16; ++k) qk[k] *= 0.125f;       // fold SCALE

    // pp[j] = sum_c qk[c] * Wp[c][j]  (partial over own quarter, combine via shfl)
    float p0 = 0.f, p1 = 0.f, p2 = 0.f, p3 = 0.f;
#pragma unroll
    for (int k = 0; k < 16; ++k) {
        const float4 wp4 = *(const float4*)(Wp + (16 * q + k) * 4);
        p0 = fmaf(qk[k], wp4.x, p0);
        p1 = fmaf(qk[k], wp4.y, p1);
        p2 = fmaf(qk[k], wp4.z, p2);
        p3 = fmaf(qk[k], wp4.w, p3);
    }
    p0 += __shfl_xor(p0, 16); p0 += __shfl_xor(p0, 32);
    p1 += __shfl_xor(p1, 16); p1 += __shfl_xor(p1, 32);
    p2 += __shfl_xor(p2, 16); p2 += __shfl_xor(p2, 32);
    p3 += __shfl_xor(p3, 16); p3 += __shfl_xor(p3, 32);

    float* orow = ws + (size_t)pt * ST + 16 * q;
    ((float4*)orow)[0] = make_float4(qk[0],  qk[1],  qk[2],  qk[3]);
    ((float4*)orow)[1] = make_float4(qk[4],  qk[5],  qk[6],  qk[7]);
    ((float4*)orow)[2] = make_float4(qk[8],  qk[9],  qk[10], qk[11]);
    ((float4*)orow)[3] = make_float4(qk[12], qk[13], qk[14], qk[15]);
    if (q == 0)
        *(float4*)(ws + (size_t)pt * ST + 64) = make_float4(p0, p1, p2, p3);
}

// ============ Kernel B: logits + softmax + vbar (the 256MB streamer) ============
// wave = 4 points, lane = (nn, s); np loaded ONCE into registers (no L2 re-read);
// zero LDS, zero barriers; in-place ws row reuse.
__global__ __launch_bounds__(256, 4) void attn_vbar_kernel(
    const float* __restrict__ xyz, const float* __restrict__ nxyz,
    const float* __restrict__ npts, float* __restrict__ ws)
{
    const int tid = threadIdx.x;
    const int lane = tid & 63;
    const int s = lane & 15;
    const int nn = lane >> 4;
    const int gpt = blockIdx.x * 16 + (tid >> 6) * 4;   // 4-point group base
    const int b = gpt >> 14;
    const int ng = gpt & (Nn - 1);
    const int pt = gpt + nn;                            // this lane's point

    const float* npb = npts + (size_t)(b * 64) * NS + (size_t)ng * 16 + lane;  // +c*NS

    // ---- np stream: 64 coalesced dword loads (256B/instr), ONCE, into regs ----
    float npv[64];
#pragma unroll
    for (int c = 0; c < 64; ++c) npv[c] = npb[(size_t)c * NS];

    // relative position (lane's (nn,s)); all loads fully coalesced (lane-linear)
    const float nx0 = nxyz[((size_t)(b * 3 + 0) * Nn + ng) * 16 + lane];
    const float nx1 = nxyz[((size_t)(b * 3 + 1) * Nn + ng) * 16 + lane];
    const float nx2 = nxyz[((size_t)(b * 3 + 2) * Nn + ng) * 16 + lane];
    const float x0 = xyz[(size_t)(b * 3 + 0) * Nn + ng + nn];
    const float x1 = xyz[(size_t)(b * 3 + 1) * Nn + ng + nn];
    const float x2 = xyz[(size_t)(b * 3 + 2) * Nn + ng + nn];
    const float d0 = x0 - nx0, d1 = x1 - nx1, d2 = x2 - nx2;
    const float dn = sqrtf(d0 * d0 + d1 * d1 + d2 * d2);

    const float* qrow = ws + (size_t)pt * ST;

    // ---- logit = qk . np  (np from regs; qk: 16B broadcast loads, L2-hot) ----
    float l0 = 0.f, l1 = 0.f, l2 = 0.f, l3 = 0.f;
#pragma unroll
    for (int jc = 0; jc < 16; ++jc) {
        const float4 qq = *(const float4*)(qrow + 4 * jc);
        l0 = fmaf(qq.x, npv[4 * jc + 0], l0);
        l1 = fmaf(qq.y, npv[4 * jc + 1], l1);
        l2 = fmaf(qq.z, npv[4 * jc + 2], l2);
        l3 = fmaf(qq.w, npv[4 * jc + 3], l3);
    }
    const float4 ppv = *(const float4*)(qrow + 64);
    float logit = (l0 + l1) + (l2 + l3);
    logit += ppv.x * d0 + ppv.y * d1 + ppv.z * d2 + ppv.w * dn;
    // (bp term constant in s -> cancels in softmax)

    // ---- softmax over s (pure DPP in rows of 16) ----
    const float mx = rmax16(logit);
    const float e = __expf(logit - mx);
    const float se = rsum16(e);
    const float attn = e / se;

    // ---- vbar[c] = sum_s attn*np[c][s], entirely from registers ----
    // all qrow reads above precede these in-place writes (program order,
    // row is wave-private) -> safe buffer reuse.
    float* vrow = ws + (size_t)pt * ST;
#pragma unroll
    for (int k = 0; k < 4; ++k) {               // k compile-time -> static everywhere
        float sel = 0.f;
#pragma unroll
        for (int c2 = 0; c2 < 16; ++c2) {
            const float r = rsum16(attn * npv[16 * k + c2]);
            sel = (s == c2) ? r : sel;          // lane keeps c = 16k + s
        }
        vrow[16 * k + s] = sel;                 // 16 consec dwords x4 pts / instr
    }
    const float t0 = rsum16(attn * d0);
    const float t1 = rsum16(attn * d1);
    const float t2 = rsum16(attn * d2);
    if (s < 4) {
        const float tv = (s == 0) ? t0 : (s == 1) ? t1 : (s == 2) ? t2 : 0.f;
        vrow[64 + s] = tv;                      // tail channels 64..66, slot 67 = 0
    }
}

// ================= Kernel C: out[o] = Wv[o,:] . vbar =================
// lane = o, Wv row in regs; vbar via full-wave 16B broadcast loads; no LDS.
__global__ __launch_bounds__(256, 4) void out_kernel(
    const float* __restrict__ Wv, const float* __restrict__ ws,
    float* __restrict__ out)
{
    const int tid = threadIdx.x;
    const int lane = tid & 63;                  // output channel o
    const int cpt = blockIdx.x * 64 + (tid >> 6) * 16;   // 16 consecutive points
    const int b = cpt >> 14;
    const int n0 = cpt & (Nn - 1);

    float wv[68];
#pragma unroll
    for (int c = 0; c < 67; ++c) wv[c] = Wv[lane * 67 + c];
    wv[67] = 0.f;                               // pairs with the zeroed ws slot 67

    float acc[16];
    const float* vbase = ws + (size_t)cpt * ST;
#pragma unroll
    for (int i = 0; i < 16; ++i) {
        float a0 = 0.f, a1 = 0.f, a2 = 0.f, a3 = 0.f;
#pragma unroll
        for (int j = 0; j < 17; ++j) {
            const float4 vv = *(const float4*)(vbase + i * ST + 4 * j);  // 1-addr broadcast
            a0 = fmaf(vv.x, wv[4 * j + 0], a0);
            a1 = fmaf(vv.y, wv[4 * j + 1], a1);
            a2 = fmaf(vv.z, wv[4 * j + 2], a2);
            a3 = fmaf(vv.w, wv[4 * j + 3], a3);
        }
        acc[i] = (a0 + a1) + (a2 + a3);
    }
    // 64B contiguous per lane; 4-wave block covers 256B runs per (b,o) row
    float* orow = out + (size_t)(b * 64 + lane) * Nn + n0;
    ((float4*)orow)[0] = make_float4(acc[0],  acc[1],  acc[2],  acc[3]);
    ((float4*)orow)[1] = make_float4(acc[4],  acc[5],  acc[6],  acc[7]);
    ((float4*)orow)[2] = make_float4(acc[8],  acc[9],  acc[10], acc[11]);
    ((float4*)orow)[3] = make_float4(acc[12], acc[13], acc[14], acc[15]);
}

extern "C" void kernel_launch(void* const* d_in, const int* in_sizes, int n_in,
                              void* d_out, int out_size, void* d_ws, size_t ws_size,
                              hipStream_t stream) {
    const float* xyz    = (const float*)d_in[0];
    const float* nxyz   = (const float*)d_in[1];
    const float* points = (const float*)d_in[2];
    const float* npts   = (const float*)d_in[3];
    const float* Wk     = (const float*)d_in[4];
    const float* Wv     = (const float*)d_in[5];
    const float* Wp     = (const float*)d_in[6];
    // d_in[7] = bp — unused: constant-in-s logit shift cancels in softmax
    float* out = (float*)d_out;
    float* ws = (float*)d_ws;   // [65536][68] fp32 = 17.8 MB, fully rewritten each call

    hipLaunchKernelGGL(qkpp_kernel,      dim3(1024), dim3(256), 0, stream,
                       points, Wk, Wp, ws);
    hipLaunchKernelGGL(attn_vbar_kernel, dim3(4096), dim3(256), 0, stream,
                       xyz, nxyz, npts, ws);
    hipLaunchKernelGGL(out_kernel,       dim3(1024), dim3(256), 0, stream,
                       Wv, ws, out);
}

// Round 7
// 118.129 us; speedup vs baseline: 2.5775x; 1.3378x over previous
//
#include <hip/hip_runtime.h>
#include <math.h>

constexpr int Nn = 16384;
constexpr int ST = 68;                      // ws row stride (dwords): 64 qk + 4 pp
constexpr size_t NS = (size_t)Nn * 16;      // dwords per channel plane of npts

// ---- DPP helpers (pure VALU cross-lane, rows of 16) ----
template <int CTRL>
__device__ __forceinline__ float dpp_f(float x) {
    return __int_as_float(
        __builtin_amdgcn_update_dpp(0, __float_as_int(x), CTRL, 0xF, 0xF, false));
}
__device__ __forceinline__ float rsum16(float v) {
    v += dpp_f<0x128>(v); v += dpp_f<0x124>(v);
    v += dpp_f<0x122>(v); v += dpp_f<0x121>(v);
    return v;
}
__device__ __forceinline__ float rmax16(float v) {
    v = fmaxf(v, dpp_f<0x128>(v)); v = fmaxf(v, dpp_f<0x124>(v));
    v = fmaxf(v, dpp_f<0x122>(v)); v = fmaxf(v, dpp_f<0x121>(v));
    return v;
}

// ================= Kernel A: qk = Wk^T (q*scale), pp = Wp^T qk =================
// thread = (point, 16-channel quarter); no LDS.
__global__ __launch_bounds__(256, 4) void qkpp_kernel(
    const float* __restrict__ points, const float* __restrict__ Wk,
    const float* __restrict__ Wp, float* __restrict__ ws)
{
    const int tid = threadIdx.x;
    const int lane = tid & 63;
    const int q = lane >> 4;                            // quarter 0..3
    const int pt = blockIdx.x * 64 + (tid >> 6) * 16 + (lane & 15);
    const int b = pt >> 14;
    const int n = pt & (Nn - 1);

    float qk[16];
#pragma unroll
    for (int k = 0; k < 16; ++k) qk[k] = 0.f;

    const float* prow = points + (size_t)b * 64 * Nn + n;
    const float* wkq = Wk + 16 * q;
#pragma unroll 4
    for (int c = 0; c < 64; ++c) {
        const float qv = prow[(size_t)c * Nn];          // coalesced (16n x4 dup -> 64B)
        const float4 w0 = *(const float4*)(wkq + c * 64 + 0);   // wave-broadcast (4 distinct)
        const float4 w1 = *(const float4*)(wkq + c * 64 + 4);
        const float4 w2 = *(const float4*)(wkq + c * 64 + 8);
        const float4 w3 = *(const float4*)(wkq + c * 64 + 12);
        qk[0]  = fmaf(qv, w0.x, qk[0]);  qk[1]  = fmaf(qv, w0.y, qk[1]);
        qk[2]  = fmaf(qv, w0.z, qk[2]);  qk[3]  = fmaf(qv, w0.w, qk[3]);
        qk[4]  = fmaf(qv, w1.x, qk[4]);  qk[5]  = fmaf(qv, w1.y, qk[5]);
        qk[6]  = fmaf(qv, w1.z, qk[6]);  qk[7]  = fmaf(qv, w1.w, qk[7]);
        qk[8]  = fmaf(qv, w2.x, qk[8]);  qk[9]  = fmaf(qv, w2.y, qk[9]);
        qk[10] = fmaf(qv, w2.z, qk[10]); qk[11] = fmaf(qv, w2.w, qk[11]);
        qk[12] = fmaf(qv, w3.x, qk[12]); qk[13] = fmaf(qv, w3.y, qk[13]);
        qk[14] = fmaf(qv, w3.z, qk[14]); qk[15] = fmaf(qv, w3.w, qk[15]);
    }
#pragma unroll
    for (int k = 0; k < 16; ++k) qk[k] *= 0.125f;       // fold SCALE

    // pp[j] = sum_c qk[c] * Wp[c][j]  (partial over own quarter, combine via shfl)
    float p0 = 0.f, p1 = 0.f, p2 = 0.f, p3 = 0.f;
#pragma unroll
    for (int k = 0; k < 16; ++k) {
        const float4 wp4 = *(const float4*)(Wp + (16 * q + k) * 4);
        p0 = fmaf(qk[k], wp4.x, p0);
        p1 = fmaf(qk[k], wp4.y, p1);
        p2 = fmaf(qk[k], wp4.z, p2);
        p3 = fmaf(qk[k], wp4.w, p3);
    }
    p0 += __shfl_xor(p0, 16); p0 += __shfl_xor(p0, 32);
    p1 += __shfl_xor(p1, 16); p1 += __shfl_xor(p1, 32);
    p2 += __shfl_xor(p2, 16); p2 += __shfl_xor(p2, 32);
    p3 += __shfl_xor(p3, 16); p3 += __shfl_xor(p3, 32);

    float* orow = ws + (size_t)pt * ST + 16 * q;
    ((float4*)orow)[0] = make_float4(qk[0],  qk[1],  qk[2],  qk[3]);
    ((float4*)orow)[1] = make_float4(qk[4],  qk[5],  qk[6],  qk[7]);
    ((float4*)orow)[2] = make_float4(qk[8],  qk[9],  qk[10], qk[11]);
    ((float4*)orow)[3] = make_float4(qk[12], qk[13], qk[14], qk[15]);
    if (q == 0)
        *(float4*)(ws + (size_t)pt * ST + 64) = make_float4(p0, p1, p2, p3);
}

// ====== Kernel B: logits + softmax + vbar + Wv matvec (fused; the streamer) ======
// wave = 4 points, lane = (nn, s); np loaded once into regs; Wv^T staged in LDS;
// out accumulated in the vbar loop (vbar[c] is live in all row lanes), stored direct.
__global__ __launch_bounds__(256, 4) void attn_out_kernel(
    const float* __restrict__ xyz, const float* __restrict__ nxyz,
    const float* __restrict__ npts, const float* __restrict__ Wv,
    const float* __restrict__ ws, float* __restrict__ out)
{
    __shared__ float wvT[67 * 68];              // [c][o], stride 68 (b128 reads 2-way = free)

    const int tid = threadIdx.x;
    // one-time Wv transpose-stage (coalesced global read)
    for (int idx = tid; idx < 64 * 67; idx += 256) {
        const int o = idx / 67, c = idx - o * 67;
        wvT[c * 68 + o] = Wv[idx];
    }
    __syncthreads();

    const int lane = tid & 63;
    const int s = lane & 15;
    const int nn = lane >> 4;
    const int gpt = blockIdx.x * 16 + (tid >> 6) * 4;   // 4-point group base
    const int b = gpt >> 14;
    const int ng = gpt & (Nn - 1);
    const int pt = gpt + nn;                            // this lane's point

    const float* npb = npts + (size_t)(b * 64) * NS + (size_t)ng * 16 + lane;  // +c*NS

    // ---- np stream: 64 coalesced dword loads (256B/instr), ONCE, into regs ----
    float npv[64];
#pragma unroll
    for (int c = 0; c < 64; ++c) npv[c] = npb[(size_t)c * NS];

    // relative position (lane's (nn,s)); all loads fully coalesced (lane-linear)
    const float nx0 = nxyz[((size_t)(b * 3 + 0) * Nn + ng) * 16 + lane];
    const float nx1 = nxyz[((size_t)(b * 3 + 1) * Nn + ng) * 16 + lane];
    const float nx2 = nxyz[((size_t)(b * 3 + 2) * Nn + ng) * 16 + lane];
    const float x0 = xyz[(size_t)(b * 3 + 0) * Nn + ng + nn];
    const float x1 = xyz[(size_t)(b * 3 + 1) * Nn + ng + nn];
    const float x2 = xyz[(size_t)(b * 3 + 2) * Nn + ng + nn];
    const float d0 = x0 - nx0, d1 = x1 - nx1, d2 = x2 - nx2;
    const float dn = sqrtf(d0 * d0 + d1 * d1 + d2 * d2);

    const float* qrow = ws + (size_t)pt * ST;

    // ---- logit = qk . np  (np from regs; qk: 16B broadcast loads, L2-hot) ----
    float l0 = 0.f, l1 = 0.f, l2 = 0.f, l3 = 0.f;
#pragma unroll
    for (int jc = 0; jc < 16; ++jc) {
        const float4 qq = *(const float4*)(qrow + 4 * jc);
        l0 = fmaf(qq.x, npv[4 * jc + 0], l0);
        l1 = fmaf(qq.y, npv[4 * jc + 1], l1);
        l2 = fmaf(qq.z, npv[4 * jc + 2], l2);
        l3 = fmaf(qq.w, npv[4 * jc + 3], l3);
    }
    const float4 ppv = *(const float4*)(qrow + 64);
    float logit = (l0 + l1) + (l2 + l3);
    logit += ppv.x * d0 + ppv.y * d1 + ppv.z * d2 + ppv.w * dn;
    // (bp term constant in s -> cancels in softmax)

    // ---- softmax over s (pure DPP in rows of 16) ----
    const float mx = rmax16(logit);
    const float e = __expf(logit - mx);
    const float se = rsum16(e);
    const float attn = e / se;

    // ---- fused vbar + Wv matvec ----
    // rsum16 puts vbar[c] in ALL 16 lanes of row nn; lane (nn,s) owns o = 4s..4s+3.
    float a0 = 0.f, a1 = 0.f, a2 = 0.f, a3 = 0.f;
#pragma unroll
    for (int c = 0; c < 64; ++c) {
        const float r = rsum16(attn * npv[c]);                  // vbar[c, nn]
        const float4 wq = *(const float4*)&wvT[c * 68 + 4 * s]; // Wv[4s..4s+3][c]
        a0 = fmaf(r, wq.x, a0);
        a1 = fmaf(r, wq.y, a1);
        a2 = fmaf(r, wq.z, a2);
        a3 = fmaf(r, wq.w, a3);
    }
    {   // tail channels 64..66 (= tmp d0,d1,d2)
        const float t0 = rsum16(attn * d0);
        const float t1 = rsum16(attn * d1);
        const float t2 = rsum16(attn * d2);
        const float4 wA = *(const float4*)&wvT[64 * 68 + 4 * s];
        const float4 wB = *(const float4*)&wvT[65 * 68 + 4 * s];
        const float4 wC = *(const float4*)&wvT[66 * 68 + 4 * s];
        a0 = fmaf(t0, wA.x, a0); a1 = fmaf(t0, wA.y, a1);
        a2 = fmaf(t0, wA.z, a2); a3 = fmaf(t0, wA.w, a3);
        a0 = fmaf(t1, wB.x, a0); a1 = fmaf(t1, wB.y, a1);
        a2 = fmaf(t1, wB.z, a2); a3 = fmaf(t1, wB.w, a3);
        a0 = fmaf(t2, wC.x, a0); a1 = fmaf(t2, wC.y, a1);
        a2 = fmaf(t2, wC.z, a2); a3 = fmaf(t2, wC.w, a3);
    }

    // ---- direct stores: out[o = 4s+j][ng+nn]; 16 x 16B segments per instr,
    //      sibling waves of the block complete each 64B line in L2 ----
    float* ob = out + ((size_t)(b * 64 + 4 * s) * Nn) + ng + nn;
    ob[0]          = a0;
    ob[(size_t)Nn]     = a1;
    ob[(size_t)Nn * 2] = a2;
    ob[(size_t)Nn * 3] = a3;
}

extern "C" void kernel_launch(void* const* d_in, const int* in_sizes, int n_in,
                              void* d_out, int out_size, void* d_ws, size_t ws_size,
                              hipStream_t stream) {
    const float* xyz    = (const float*)d_in[0];
    const float* nxyz   = (const float*)d_in[1];
    const float* points = (const float*)d_in[2];
    const float* npts   = (const float*)d_in[3];
    const float* Wk     = (const float*)d_in[4];
    const float* Wv     = (const float*)d_in[5];
    const float* Wp     = (const float*)d_in[6];
    // d_in[7] = bp — unused: constant-in-s logit shift cancels in softmax
    float* out = (float*)d_out;
    float* ws = (float*)d_ws;   // [65536][68] fp32 = 17.8 MB, fully rewritten each call

    hipLaunchKernelGGL(qkpp_kernel,     dim3(1024), dim3(256), 0, stream,
                       points, Wk, Wp, ws);
    hipLaunchKernelGGL(attn_out_kernel, dim3(4096), dim3(256), 0, stream,
                       xyz, nxyz, npts, Wv, ws, out);
}